// Round 9
// baseline (394.248 us; speedup 1.0000x reference)
//
#include <hip/hip_runtime.h>
#include <stdint.h>

// ---------------------------------------------------------------------------
// SparseResUQueryNet: bitmap+rank sparse conv -> time max-pool -> sparse conv
//
// Round-9 = round-8 + :
//   - z-triple probes: the 3 dz-taps of each (dx,dy) group live in ONE u64
//     bitmap word (except z%64 boundary, ~2.4%, one extra load). 9 probing
//     lanes instead of 27; issued probe loads 54 -> ~19 per voxel/point.
//   - XCD-contiguous swizzle for K1/K2: vb=(blk&7)*nper+(blk>>3) gives each
//     XCD a contiguous voxel range so it streams only its 1/8 of the 50MB
//     hist metadata (r8: every XCD re-streamed it, FETCH ~3x footprint).
//   - no 41MB pooled memset: zero_multi kernel zeroes only the ~1% rows with
//     >=2 contributors (the only ones read-modify-written via CAS-max).
// ---------------------------------------------------------------------------

#define TPB 256
#define SCAN_WPT 8
typedef unsigned long long u64;
typedef unsigned int u32;
typedef unsigned short u16;

// f32 -> RNE bf16 -> monotone u16 (order-preserving; 0 is below all reals)
__device__ __forceinline__ u32 trans16(float x) {
    u32 b = __float_as_uint(x);
    u32 bf = (b + 0x7FFFu + ((b >> 16) & 1u)) >> 16;
    return ((bf & 0x8000u) ? (~bf) : (bf | 0x8000u)) & 0xFFFFu;
}
__device__ __forceinline__ float detrans16(u32 u) {
    u32 orig = (u & 0x8000u) ? (u & 0x7FFFu) : ((~u) & 0xFFFFu);
    return __uint_as_float(orig << 16);
}

// probe the 3 consecutive keys {nk-1, nk, nk+1}: hit bits + ranks ------------
struct Probe3 { u32 h; u32 r0, r1, r2; };
__device__ __forceinline__ Probe3 probe3(const u64* __restrict__ bm,
                                         const u32* __restrict__ rank, int nk) {
    Probe3 P;
    int wi = nk >> 6, zb = nk & 63;
    u64 wA = bm[wi];
    u32 rA = rank[wi];
    if (zb >= 1 && zb <= 62) {                       // common: all in one word
        u32 hl = (u32)((wA >> (zb - 1)) & 1ull);
        u32 hm = (u32)((wA >> zb) & 1ull);
        u32 hr = (u32)((wA >> (zb + 1)) & 1ull);
        P.r0 = rA + (u32)__popcll(wA & ((1ull << (zb - 1)) - 1ull));
        P.r1 = P.r0 + hl;
        P.r2 = P.r1 + hm;
        P.h = hl | (hm << 1) | (hr << 2);
    } else if (zb == 0) {                            // nk-1 in previous word
        u64 wB = bm[wi - 1];
        u32 hl = (u32)(wB >> 63);
        u32 hm = (u32)(wA & 1ull);
        u32 hr = (u32)((wA >> 1) & 1ull);
        P.r0 = rank[wi - 1] + (u32)__popcll(wB & 0x7FFFFFFFFFFFFFFFull);
        P.r1 = rA;
        P.r2 = rA + hm;
        P.h = hl | (hm << 1) | (hr << 2);
    } else {                                         // zb==63: nk+1 in next word
        u64 wC = bm[wi + 1];
        u32 hl = (u32)((wA >> 62) & 1ull);
        u32 hm = (u32)(wA >> 63);
        u32 hr = (u32)(wC & 1ull);
        P.r0 = rA + (u32)__popcll(wA & ((1ull << 62) - 1ull));
        P.r1 = P.r0 + hl;
        P.r2 = rank[wi + 1];
        P.h = hl | (hm << 1) | (hr << 2);
    }
    return P;
}

// K1: set existence bits; second pool contributor marks multi ----------------
__global__ void build_bitmaps_kernel(const int4* __restrict__ hc,
                                     const int* __restrict__ hb,
                                     int n, int nblk,
                                     u64* __restrict__ hist_bm,
                                     u64* __restrict__ pool_bm,
                                     u64* __restrict__ multi_bm) {
    int nper = (nblk + 7) >> 3;
    int vb = ((int)blockIdx.x & 7) * nper + ((int)blockIdx.x >> 3);
    int j = vb * TPB + (int)threadIdx.x;
    if (j >= n) return;
    int4 c = hc[j];                                   // (t,x,y,z)
    int key = ((c.x * 256 + c.y) * 256 + c.z) * 256 + c.w;
    atomicOr(&hist_bm[key >> 6], 1ull << (key & 63));
    int pk = ((hb[j] * 256 + c.y) * 256 + c.z) * 256 + c.w;
    u64 bit = 1ull << (pk & 63);
    u64 old = atomicOr(&pool_bm[pk >> 6], bit);
    if (old & bit) atomicOr(&multi_bm[pk >> 6], bit); // >=2 contributors
}

// scan stage 1: per-block popcount sums --------------------------------------
__global__ void scan_sum_kernel(const u64* __restrict__ bm, u32* __restrict__ bsum) {
    __shared__ u32 s[TPB];
    int t = threadIdx.x;
    size_t base = ((size_t)blockIdx.x * TPB + t) * SCAN_WPT;
    u32 acc = 0;
#pragma unroll
    for (int i = 0; i < SCAN_WPT; i++) acc += __popcll(bm[base + i]);
    s[t] = acc; __syncthreads();
    for (int off = TPB / 2; off > 0; off >>= 1) {
        if (t < off) s[t] += s[t + off];
        __syncthreads();
    }
    if (t == 0) bsum[blockIdx.x] = s[0];
}

// scan stage 2: exclusive scan of block sums (count <= 2048), one block ------
__global__ void scan_partials_kernel(u32* __restrict__ bsum, int count) {
    __shared__ u32 s[TPB];
    int t = threadIdx.x;
    int wpt = count >> 8;                              // 8 (hist) or 1 (pool)
    u32 v[8]; u32 acc = 0;
    for (int i = 0; i < wpt; i++) { v[i] = bsum[t * wpt + i]; acc += v[i]; }
    s[t] = acc; __syncthreads();
    for (int off = 1; off < TPB; off <<= 1) {          // inclusive Hillis-Steele
        u32 x = (t >= off) ? s[t - off] : 0;
        __syncthreads();
        s[t] += x;
        __syncthreads();
    }
    u32 run = s[t] - acc;                              // exclusive base
    for (int i = 0; i < wpt; i++) { bsum[t * wpt + i] = run; run += v[i]; }
}

// scan stage 3: per-word exclusive rank --------------------------------------
__global__ void scan_apply_kernel(const u64* __restrict__ bm,
                                  const u32* __restrict__ bsum,
                                  u32* __restrict__ rank) {
    __shared__ u32 s[TPB];
    int t = threadIdx.x;
    size_t base = ((size_t)blockIdx.x * TPB + t) * SCAN_WPT;
    u32 pc[SCAN_WPT]; u32 acc = 0;
#pragma unroll
    for (int i = 0; i < SCAN_WPT; i++) { pc[i] = __popcll(bm[base + i]); acc += pc[i]; }
    s[t] = acc; __syncthreads();
    for (int off = 1; off < TPB; off <<= 1) {
        u32 x = (t >= off) ? s[t - off] : 0;
        __syncthreads();
        s[t] += x;
        __syncthreads();
    }
    u32 run = bsum[blockIdx.x] + s[t] - acc;
#pragma unroll
    for (int i = 0; i < SCAN_WPT; i++) { rank[base + i] = run; run += pc[i]; }
}

// zero only the pooled rows with >=2 contributors (CAS-max targets) ----------
__global__ void zero_multi_kernel(const u64* __restrict__ multi_bm,
                                  const u64* __restrict__ pool_bm,
                                  const u32* __restrict__ pool_rank,
                                  u32* __restrict__ pooled, int NW) {
    int w = blockIdx.x * blockDim.x + threadIdx.x;
    if (w >= NW) return;
    u64 mw = multi_bm[w];
    if (!mw) return;
    u64 pw = pool_bm[w];
    u32 rk = pool_rank[w];
    while (mw) {
        int b = __ffsll((unsigned long long)mw) - 1; mw &= mw - 1;
        u32 slot = rk + (u32)__popcll(pw & ((1ull << b) - 1ull));
        u32* P = pooled + (size_t)slot * 16;
#pragma unroll
        for (int i = 0; i < 16; i++) P[i] = 0;
    }
}

// K2: half-wave per voxel: 27-tap conv (1->32) + packed pooled write --------
__global__ void bb_pool_kernel(const int4* __restrict__ hc,
                               const int* __restrict__ hb,
                               const float* __restrict__ hf,
                               const float* __restrict__ Wbb,   // [27*32]
                               int n, int nblk,
                               const u64* __restrict__ hist_bm,
                               const u32* __restrict__ hist_rank,
                               const u64* __restrict__ pool_bm,
                               const u32* __restrict__ pool_rank,
                               const u64* __restrict__ multi_bm,
                               u32* __restrict__ pooled) {
    int nper = (nblk + 7) >> 3;
    int vb = ((int)blockIdx.x & 7) * nper + ((int)blockIdx.x >> 3);
    int p = (vb * TPB + (int)threadIdx.x) >> 5;        // voxel index
    if (p >= n) return;
    int lane = threadIdx.x & 63;
    int hb32 = lane & 32;                              // half base within wave
    int f = lane & 31;                                 // feature / probe lane

    int4 c = hc[p];
    int key = ((c.x * 256 + c.y) * 256 + c.z) * 256 + c.w;
    int pk = ((hb[p] * 256 + c.y) * 256 + c.z) * 256 + c.w;

    // pool-side loads issued early (independent of probe chain)
    u64 pword = pool_bm[pk >> 6];
    u32 prank = pool_rank[pk >> 6];
    u64 mword = multi_bm[pk >> 6];

    float fv0 = 0.f, fv1 = 0.f, fv2 = 0.f;
    u32 h3 = 0;
    if (f < 9) {                                       // 9 (dx,dy) groups
        int nk = key + (f / 3 - 1) * 65536 + (f % 3 - 1) * 256;
        Probe3 P = probe3(hist_bm, hist_rank, nk);
        h3 = P.h;                                      // rank == row index j
        if (h3 & 1u) fv0 = hf[P.r0];
        if (h3 & 2u) fv1 = hf[P.r1];
        if (h3 & 4u) fv2 = hf[P.r2];
    }
    u64 B0 = __ballot(h3 & 1u);
    u64 B1 = __ballot(h3 & 2u);
    u64 B2 = __ballot(h3 & 4u);
    u32 m0 = (u32)(B0 >> hb32) & 0x1FFu;
    u32 m1 = (u32)(B1 >> hb32) & 0x1FFu;
    u32 m2 = (u32)(B2 >> hb32) & 0x1FFu;

    float acc = 0.f;                                   // tap b = l*3 + dz+1
    while (m0) { int l = __ffs(m0) - 1; m0 &= m0 - 1;
        acc = fmaf(__shfl(fv0, hb32 + l), Wbb[(l * 3 + 0) * 32 + f], acc); }
    while (m1) { int l = __ffs(m1) - 1; m1 &= m1 - 1;
        acc = fmaf(__shfl(fv1, hb32 + l), Wbb[(l * 3 + 1) * 32 + f], acc); }
    while (m2) { int l = __ffs(m2) - 1; m2 &= m2 - 1;
        acc = fmaf(__shfl(fv2, hb32 + l), Wbb[(l * 3 + 2) * 32 + f], acc); }

    int bit = pk & 63;
    int slot = (int)(prank + (u32)__popcll(pword & ((1ull << bit) - 1ull)));
    bool multi = (mword >> bit) & 1ull;

    u32 tv = trans16(acc);
    u32 packed = tv | (((u32)__shfl_down((int)tv, 1)) << 16);  // pair (f, f+1)
    if ((f & 1) == 0) {
        u32* addr = pooled + (size_t)slot * 16 + (f >> 1);
        if (!multi) {
            *addr = packed;                            // ~99%: plain store
        } else {
            u32 oldv = *addr;
            while (true) {
                u32 lo = max(oldv & 0xFFFFu, packed & 0xFFFFu);
                u32 hi = max(oldv >> 16, packed >> 16);
                u32 mx = lo | (hi << 16);
                if (mx == oldv) break;
                u32 prev = atomicCAS(addr, oldv, mx);
                if (prev == oldv) break;
                oldv = prev;
            }
        }
    }
}

// K3: half-wave per query point: 27-tap conv (32->32) + output --------------
__global__ void query_kernel(const int4* __restrict__ qc,
                             const float* __restrict__ pts,      // stride 5
                             const float* __restrict__ Wc,       // [27][32][32]
                             int m,
                             const u64* __restrict__ pool_bm,
                             const u32* __restrict__ pool_rank,
                             const u16* __restrict__ pooled16,
                             float* __restrict__ out) {
    int p = (blockIdx.x * blockDim.x + threadIdx.x) >> 5;
    if (p >= m) return;
    int lane = threadIdx.x & 63;
    int hb32 = lane & 32;
    int f = lane & 31;

    int4 c = qc[p];                                    // (b,x,y,z)
    int qk = ((c.x * 256 + c.y) * 256 + c.z) * 256 + c.w;

    u32 h3 = 0; u32 s0 = 0, s1 = 0, s2 = 0;
    if (f < 9) {
        int nk = qk + (f / 3 - 1) * 65536 + (f % 3 - 1) * 256;
        Probe3 P = probe3(pool_bm, pool_rank, nk);
        h3 = P.h; s0 = P.r0; s1 = P.r1; s2 = P.r2;     // ranks = pooled slots
    }
    u64 B0 = __ballot(h3 & 1u);
    u64 B1 = __ballot(h3 & 2u);
    u64 B2 = __ballot(h3 & 4u);
    u32 m0 = (u32)(B0 >> hb32) & 0x1FFu;
    u32 m1 = (u32)(B1 >> hb32) & 0x1FFu;
    u32 m2 = (u32)(B2 >> hb32) & 0x1FFu;

    float acc = 0.f;
#pragma unroll 1
    for (int j = 0; j < 3; j++) {
        u32 mm = (j == 0) ? m0 : (j == 1) ? m1 : m2;
        while (mm) {
            int l = __ffs(mm) - 1; mm &= mm - 1;
            int slot = __shfl((int)((j == 0) ? s0 : (j == 1) ? s1 : s2), hb32 + l);
            float pv = detrans16(pooled16[(size_t)slot * 32 + f]);  // 64B row
            const float* W = Wc + (l * 3 + j) * 1024 + f;           // k-major
#pragma unroll
            for (int k = 0; k < 32; k++) {
                float pk_ = __shfl(pv, hb32 + k);      // broadcast P[k]
                acc = fmaf(pk_, W[k * 32], acc);       // coalesced 128B W line
            }
        }
    }

    out[(size_t)p * 36 + 4 + f] = acc;                 // features, coalesced
    if (f < 4) out[(size_t)p * 36 + f] = pts[p * 5 + f];  // head
}

// ---------------------------------------------------------------------------
extern "C" void kernel_launch(void* const* d_in, const int* in_sizes, int n_in,
                              void* d_out, int out_size, void* d_ws, size_t ws_size,
                              hipStream_t stream) {
    const float* hfeat   = (const float*)d_in[0];   // [n,1]
    const float* pts     = (const float*)d_in[1];   // [m,5]
    const float* Wbb     = (const float*)d_in[2];   // [27,1,32]
    const float* Wconv   = (const float*)d_in[3];   // [27,32,32]
    const int4*  hcoords = (const int4*)d_in[4];    // [n,4] sorted by packed key
    const int*   hbatch  = (const int*)d_in[5];     // [n]
    const int4*  qcoords = (const int4*)d_in[6];    // [m,4]
    int n = in_sizes[0];
    int m = in_sizes[1] / 5;

    const int NW_H = 1 << 22;                       // 2^28 bits / 64
    const int NW_P = 1 << 19;                       // 2^25 bits / 64
    const int GB_H = NW_H / (TPB * SCAN_WPT);       // 2048
    const int GB_P = NW_P / (TPB * SCAN_WPT);       // 256

    // layout: [hist_bm | pool_bm | multi_bm] zeroed; ranks/bsums/pooled after
    char* w = (char*)d_ws;
    char* zbase = w;
    u64* hist_bm      = (u64*)w;       w += (size_t)NW_H * 8;
    u64* pool_bm      = (u64*)w;       w += (size_t)NW_P * 8;
    u64* multi_bm     = (u64*)w;       w += (size_t)NW_P * 8;
    size_t zbytes = (size_t)(w - zbase);
    u32* hist_rank    = (u32*)w;       w += (size_t)NW_H * 4;
    u32* pool_rank    = (u32*)w;       w += (size_t)NW_P * 4;
    u32* bsum_h       = (u32*)w;       w += (size_t)GB_H * 4;
    u32* bsum_p       = (u32*)w;       w += (size_t)GB_P * 4;
    u32* pooled       = (u32*)w;       // n*64 bytes, NOT memset (zero_multi)

    hipMemsetAsync(zbase, 0x00, zbytes, stream);

    int gb_n   = (n + TPB - 1) / TPB;
    int gb_n1  = ((gb_n + 7) / 8) * 8;                 // XCD-swizzled grids
    int gb_n32 = (int)(((long long)n * 32 + TPB - 1) / TPB);
    int gb_n32s = ((gb_n32 + 7) / 8) * 8;
    int gb_m32 = (int)(((long long)m * 32 + TPB - 1) / TPB);
    int gb_zm  = (NW_P + TPB - 1) / TPB;

    build_bitmaps_kernel<<<gb_n1, TPB, 0, stream>>>(hcoords, hbatch, n, gb_n,
                                                    hist_bm, pool_bm, multi_bm);
    scan_sum_kernel<<<GB_H, TPB, 0, stream>>>(hist_bm, bsum_h);
    scan_partials_kernel<<<1, TPB, 0, stream>>>(bsum_h, GB_H);
    scan_apply_kernel<<<GB_H, TPB, 0, stream>>>(hist_bm, bsum_h, hist_rank);
    scan_sum_kernel<<<GB_P, TPB, 0, stream>>>(pool_bm, bsum_p);
    scan_partials_kernel<<<1, TPB, 0, stream>>>(bsum_p, GB_P);
    scan_apply_kernel<<<GB_P, TPB, 0, stream>>>(pool_bm, bsum_p, pool_rank);
    zero_multi_kernel<<<gb_zm, TPB, 0, stream>>>(multi_bm, pool_bm, pool_rank,
                                                 pooled, NW_P);
    bb_pool_kernel<<<gb_n32s, TPB, 0, stream>>>(hcoords, hbatch, hfeat, Wbb,
                                                n, gb_n32,
                                                hist_bm, hist_rank,
                                                pool_bm, pool_rank, multi_bm, pooled);
    query_kernel<<<gb_m32, TPB, 0, stream>>>(qcoords, pts, Wconv, m,
                                             pool_bm, pool_rank,
                                             (const u16*)pooled, (float*)d_out);
}

// Round 10
// 380.171 us; speedup vs baseline: 1.0370x; 1.0370x over previous
//
#include <hip/hip_runtime.h>
#include <stdint.h>

// ---------------------------------------------------------------------------
// SparseResUQueryNet: bitmap+rank sparse conv -> time max-pool -> sparse conv
//
// Round-10 = round-8 kernels (27-lane parallel probes — redundant same-line
// loads keep metadata MRU in L2; r9's z-triple regressed) + :
//   - zero_multi instead of 41MB pooled memset (only ~1% rows are CAS-max'd)
//   - nontemporal stores for out (57MB) and pooled (41MB): never re-read
//     through the writing XCD's L2 -> stop evicting probe metadata
//   - fused scan dispatches (hist+pool in one grid): 11 -> 8 dispatches
// ---------------------------------------------------------------------------

#define TPB 256
#define SCAN_WPT 8
typedef unsigned long long u64;
typedef unsigned int u32;
typedef unsigned short u16;

// f32 -> RNE bf16 -> monotone u16 (order-preserving; 0 is below all reals)
__device__ __forceinline__ u32 trans16(float x) {
    u32 b = __float_as_uint(x);
    u32 bf = (b + 0x7FFFu + ((b >> 16) & 1u)) >> 16;
    return ((bf & 0x8000u) ? (~bf) : (bf | 0x8000u)) & 0xFFFFu;
}
__device__ __forceinline__ float detrans16(u32 u) {
    u32 orig = (u & 0x8000u) ? (u & 0x7FFFu) : ((~u) & 0xFFFFu);
    return __uint_as_float(orig << 16);
}

// K1: set existence bits; second pool contributor marks multi ----------------
__global__ void build_bitmaps_kernel(const int4* __restrict__ hc,
                                     const int* __restrict__ hb,
                                     int n,
                                     u64* __restrict__ hist_bm,
                                     u64* __restrict__ pool_bm,
                                     u64* __restrict__ multi_bm) {
    int j = blockIdx.x * blockDim.x + threadIdx.x;
    if (j >= n) return;
    int4 c = hc[j];                                   // (t,x,y,z)
    int key = ((c.x * 256 + c.y) * 256 + c.z) * 256 + c.w;
    atomicOr(&hist_bm[key >> 6], 1ull << (key & 63));
    int pk = ((hb[j] * 256 + c.y) * 256 + c.z) * 256 + c.w;
    u64 bit = 1ull << (pk & 63);
    u64 old = atomicOr(&pool_bm[pk >> 6], bit);
    if (old & bit) atomicOr(&multi_bm[pk >> 6], bit); // >=2 contributors
}

// fused scan stage 1: per-block popcount sums (hist grid then pool grid) -----
__global__ void scan_sum_kernel(const u64* __restrict__ hist_bm,
                                const u64* __restrict__ pool_bm,
                                u32* __restrict__ bsum_h,
                                u32* __restrict__ bsum_p, int gbh) {
    const u64* bm; u32* bsum; int blk;
    if ((int)blockIdx.x < gbh) { bm = hist_bm; bsum = bsum_h; blk = blockIdx.x; }
    else                       { bm = pool_bm; bsum = bsum_p; blk = blockIdx.x - gbh; }
    __shared__ u32 s[TPB];
    int t = threadIdx.x;
    size_t base = ((size_t)blk * TPB + t) * SCAN_WPT;
    u32 acc = 0;
#pragma unroll
    for (int i = 0; i < SCAN_WPT; i++) acc += __popcll(bm[base + i]);
    s[t] = acc; __syncthreads();
    for (int off = TPB / 2; off > 0; off >>= 1) {
        if (t < off) s[t] += s[t + off];
        __syncthreads();
    }
    if (t == 0) bsum[blk] = s[0];
}

// fused scan stage 2: exclusive scans of both bsum arrays, one block ---------
__device__ __forceinline__ void scan_one(u32* bsum, int count, u32* s) {
    int t = threadIdx.x;
    int wpt = count >> 8;
    u32 v[8]; u32 acc = 0;
    for (int i = 0; i < wpt; i++) { v[i] = bsum[t * wpt + i]; acc += v[i]; }
    s[t] = acc; __syncthreads();
    for (int off = 1; off < TPB; off <<= 1) {          // inclusive Hillis-Steele
        u32 x = (t >= off) ? s[t - off] : 0;
        __syncthreads();
        s[t] += x;
        __syncthreads();
    }
    u32 run = s[t] - acc;                              // exclusive base
    for (int i = 0; i < wpt; i++) { bsum[t * wpt + i] = run; run += v[i]; }
}
__global__ void scan_partials_kernel(u32* __restrict__ bsum_h, int ch,
                                     u32* __restrict__ bsum_p, int cp) {
    __shared__ u32 s[TPB];
    scan_one(bsum_h, ch, s);
    __syncthreads();
    scan_one(bsum_p, cp, s);
}

// fused scan stage 3: per-word exclusive rank --------------------------------
__global__ void scan_apply_kernel(const u64* __restrict__ hist_bm,
                                  const u64* __restrict__ pool_bm,
                                  const u32* __restrict__ bsum_h,
                                  const u32* __restrict__ bsum_p,
                                  u32* __restrict__ hist_rank,
                                  u32* __restrict__ pool_rank, int gbh) {
    const u64* bm; const u32* bsum; u32* rank; int blk;
    if ((int)blockIdx.x < gbh) { bm = hist_bm; bsum = bsum_h; rank = hist_rank; blk = blockIdx.x; }
    else                       { bm = pool_bm; bsum = bsum_p; rank = pool_rank; blk = blockIdx.x - gbh; }
    __shared__ u32 s[TPB];
    int t = threadIdx.x;
    size_t base = ((size_t)blk * TPB + t) * SCAN_WPT;
    u32 pc[SCAN_WPT]; u32 acc = 0;
#pragma unroll
    for (int i = 0; i < SCAN_WPT; i++) { pc[i] = __popcll(bm[base + i]); acc += pc[i]; }
    s[t] = acc; __syncthreads();
    for (int off = 1; off < TPB; off <<= 1) {
        u32 x = (t >= off) ? s[t - off] : 0;
        __syncthreads();
        s[t] += x;
        __syncthreads();
    }
    u32 run = bsum[blk] + s[t] - acc;
#pragma unroll
    for (int i = 0; i < SCAN_WPT; i++) { rank[base + i] = run; run += pc[i]; }
}

// zero only the pooled rows with >=2 contributors (CAS-max targets) ----------
__global__ void zero_multi_kernel(const u64* __restrict__ multi_bm,
                                  const u64* __restrict__ pool_bm,
                                  const u32* __restrict__ pool_rank,
                                  u32* __restrict__ pooled, int NW) {
    int w = blockIdx.x * blockDim.x + threadIdx.x;
    if (w >= NW) return;
    u64 mw = multi_bm[w];
    if (!mw) return;
    u64 pw = pool_bm[w];
    u32 rk = pool_rank[w];
    while (mw) {
        int b = __ffsll((unsigned long long)mw) - 1; mw &= mw - 1;
        u32 slot = rk + (u32)__popcll(pw & ((1ull << b) - 1ull));
        u32* P = pooled + (size_t)slot * 16;
#pragma unroll
        for (int i = 0; i < 16; i++) P[i] = 0;
    }
}

// K2: half-wave per voxel: 27-tap conv (1->32) + packed pooled write --------
__global__ void bb_pool_kernel(const int4* __restrict__ hc,
                               const int* __restrict__ hb,
                               const float* __restrict__ hf,
                               const float* __restrict__ Wbb,   // [27*32]
                               int n,
                               const u64* __restrict__ hist_bm,
                               const u32* __restrict__ hist_rank,
                               const u64* __restrict__ pool_bm,
                               const u32* __restrict__ pool_rank,
                               const u64* __restrict__ multi_bm,
                               u32* __restrict__ pooled) {
    int p = (blockIdx.x * blockDim.x + threadIdx.x) >> 5;   // voxel index
    if (p >= n) return;
    int lane = threadIdx.x & 63;
    int hb32 = lane & 32;                              // half base within wave
    int f = lane & 31;                                 // feature / tap lane

    int4 c = hc[p];
    int key = ((c.x * 256 + c.y) * 256 + c.z) * 256 + c.w;
    int pk = ((hb[p] * 256 + c.y) * 256 + c.z) * 256 + c.w;

    // pool-side loads issued early (independent of probe chain)
    u64 pword = pool_bm[pk >> 6];
    u32 prank = pool_rank[pk >> 6];
    u64 mword = multi_bm[pk >> 6];

    float fv = 0.f;
    bool hit = false;
    if (f < 27) {
        int t1 = f / 9, rem = f - t1 * 9, t2 = rem / 3, t3 = rem - t2 * 3;
        int nk = key + (t1 - 1) * 65536 + (t2 - 1) * 256 + (t3 - 1);
        u64 word = hist_bm[nk >> 6];                   // parallel independent
        u32 rk   = hist_rank[nk >> 6];                 // loads (overlapped)
        if ((word >> (nk & 63)) & 1ull) {
            u32 r = rk + (u32)__popcll(word & ((1ull << (nk & 63)) - 1ull));
            fv = hf[r];                                // rank == row index j
            hit = true;
        }
    }
    unsigned long long bal = __ballot(hit);
    u32 mymask = (u32)(bal >> hb32);                   // this half's hit taps

    float acc = 0.f;
    while (mymask) {
        int b = __ffs(mymask) - 1;
        mymask &= mymask - 1;
        float fb = __shfl(fv, hb32 + b);               // broadcast neighbor feat
        acc = fmaf(fb, Wbb[b * 32 + f], acc);          // L1-hot 3.4KB table
    }

    int bit = pk & 63;
    int slot = (int)(prank + (u32)__popcll(pword & ((1ull << bit) - 1ull)));
    bool multi = (mword >> bit) & 1ull;

    u32 tv = trans16(acc);
    u32 packed = tv | (((u32)__shfl_down((int)tv, 1)) << 16);  // pair (f, f+1)
    if ((f & 1) == 0) {
        u32* addr = pooled + (size_t)slot * 16 + (f >> 1);
        if (!multi) {
            __builtin_nontemporal_store(packed, addr); // ~99%: NT plain store
        } else {
            u32 oldv = *addr;
            while (true) {
                u32 lo = max(oldv & 0xFFFFu, packed & 0xFFFFu);
                u32 hi = max(oldv >> 16, packed >> 16);
                u32 mx = lo | (hi << 16);
                if (mx == oldv) break;
                u32 prev = atomicCAS(addr, oldv, mx);
                if (prev == oldv) break;
                oldv = prev;
            }
        }
    }
}

// K3: half-wave per query point: 27-tap conv (32->32) + output --------------
__global__ void query_kernel(const int4* __restrict__ qc,
                             const float* __restrict__ pts,      // stride 5
                             const float* __restrict__ Wc,       // [27][32][32]
                             int m,
                             const u64* __restrict__ pool_bm,
                             const u32* __restrict__ pool_rank,
                             const u16* __restrict__ pooled16,
                             float* __restrict__ out) {
    int p = (blockIdx.x * blockDim.x + threadIdx.x) >> 5;
    if (p >= m) return;
    int lane = threadIdx.x & 63;
    int hb32 = lane & 32;
    int f = lane & 31;

    int4 c = qc[p];                                    // (b,x,y,z)
    int qk = ((c.x * 256 + c.y) * 256 + c.z) * 256 + c.w;

    int slotL = -1;
    if (f < 27) {
        int t1 = f / 9, rem = f - t1 * 9, t2 = rem / 3, t3 = rem - t2 * 3;
        int nk = qk + (t1 - 1) * 65536 + (t2 - 1) * 256 + (t3 - 1);
        u64 word = pool_bm[nk >> 6];                   // redundant same-line
        u32 rk   = pool_rank[nk >> 6];                 // loads keep L2 MRU-hot
        if ((word >> (nk & 63)) & 1ull)
            slotL = (int)(rk + (u32)__popcll(word & ((1ull << (nk & 63)) - 1ull)));
    }
    unsigned long long bal = __ballot(slotL >= 0);
    u32 mymask = (u32)(bal >> hb32);

    float acc = 0.f;
    while (mymask) {
        int b = __ffs(mymask) - 1;                     // tap index
        mymask &= mymask - 1;
        int slot = __shfl(slotL, hb32 + b);
        float pv = detrans16(pooled16[(size_t)slot * 32 + f]);  // 64B row
        const float* W = Wc + b * 1024 + f;            // W[b][k][f], k-major
#pragma unroll
        for (int k = 0; k < 32; k++) {
            float pk_ = __shfl(pv, hb32 + k);          // broadcast P[k]
            acc = fmaf(pk_, W[k * 32], acc);           // coalesced 128B W line
        }
    }

    // NT stores: out is never re-read — don't evict probe metadata from L2
    __builtin_nontemporal_store(acc, &out[(size_t)p * 36 + 4 + f]);
    if (f < 4)
        __builtin_nontemporal_store(pts[p * 5 + f], &out[(size_t)p * 36 + f]);
}

// ---------------------------------------------------------------------------
extern "C" void kernel_launch(void* const* d_in, const int* in_sizes, int n_in,
                              void* d_out, int out_size, void* d_ws, size_t ws_size,
                              hipStream_t stream) {
    const float* hfeat   = (const float*)d_in[0];   // [n,1]
    const float* pts     = (const float*)d_in[1];   // [m,5]
    const float* Wbb     = (const float*)d_in[2];   // [27,1,32]
    const float* Wconv   = (const float*)d_in[3];   // [27,32,32]
    const int4*  hcoords = (const int4*)d_in[4];    // [n,4] sorted by packed key
    const int*   hbatch  = (const int*)d_in[5];     // [n]
    const int4*  qcoords = (const int4*)d_in[6];    // [m,4]
    int n = in_sizes[0];
    int m = in_sizes[1] / 5;

    const int NW_H = 1 << 22;                       // 2^28 bits / 64
    const int NW_P = 1 << 19;                       // 2^25 bits / 64
    const int GB_H = NW_H / (TPB * SCAN_WPT);       // 2048
    const int GB_P = NW_P / (TPB * SCAN_WPT);       // 256

    // layout: [hist_bm | pool_bm | multi_bm] zeroed; ranks/bsums/pooled after
    char* w = (char*)d_ws;
    char* zbase = w;
    u64* hist_bm      = (u64*)w;       w += (size_t)NW_H * 8;
    u64* pool_bm      = (u64*)w;       w += (size_t)NW_P * 8;
    u64* multi_bm     = (u64*)w;       w += (size_t)NW_P * 8;
    size_t zbytes = (size_t)(w - zbase);
    u32* hist_rank    = (u32*)w;       w += (size_t)NW_H * 4;
    u32* pool_rank    = (u32*)w;       w += (size_t)NW_P * 4;
    u32* bsum_h       = (u32*)w;       w += (size_t)GB_H * 4;
    u32* bsum_p       = (u32*)w;       w += (size_t)GB_P * 4;
    u32* pooled       = (u32*)w;       // n*64 bytes, NOT memset (zero_multi)

    hipMemsetAsync(zbase, 0x00, zbytes, stream);

    int gb_n   = (n + TPB - 1) / TPB;
    int gb_n32 = (int)(((long long)n * 32 + TPB - 1) / TPB);
    int gb_m32 = (int)(((long long)m * 32 + TPB - 1) / TPB);
    int gb_zm  = (NW_P + TPB - 1) / TPB;

    build_bitmaps_kernel<<<gb_n, TPB, 0, stream>>>(hcoords, hbatch, n,
                                                   hist_bm, pool_bm, multi_bm);
    scan_sum_kernel<<<GB_H + GB_P, TPB, 0, stream>>>(hist_bm, pool_bm,
                                                     bsum_h, bsum_p, GB_H);
    scan_partials_kernel<<<1, TPB, 0, stream>>>(bsum_h, GB_H, bsum_p, GB_P);
    scan_apply_kernel<<<GB_H + GB_P, TPB, 0, stream>>>(hist_bm, pool_bm,
                                                       bsum_h, bsum_p,
                                                       hist_rank, pool_rank, GB_H);
    zero_multi_kernel<<<gb_zm, TPB, 0, stream>>>(multi_bm, pool_bm, pool_rank,
                                                 pooled, NW_P);
    bb_pool_kernel<<<gb_n32, TPB, 0, stream>>>(hcoords, hbatch, hfeat, Wbb, n,
                                               hist_bm, hist_rank,
                                               pool_bm, pool_rank, multi_bm, pooled);
    query_kernel<<<gb_m32, TPB, 0, stream>>>(qcoords, pts, Wconv, m,
                                             pool_bm, pool_rank,
                                             (const u16*)pooled, (float*)d_out);
}